// Round 1
// baseline (171.249 us; speedup 1.0000x reference)
//
#include <hip/hip_runtime.h>

#define SEQ    8192
#define NPOS   256            // computed rows per tile per layer
#define S_TILE 244            // valid output positions (NPOS - 12 shrink)
#define NROWS  264            // chunk rows: 256 computed + 8 zero-pad (max read row 261)
#define CSH    (NROWS*16)     // chunk stride in halves (one row = 16 halves = one ci-half = 32B)
#define NTHR   256            // 4 waves; wave w owns positions w*64 .. w*64+63 (two 32-pos tiles)
#define NREC   33             // A-records: L0:1 (tap-packed), L1:6, L2:10, L3:14, MLP:2
#define BN_HALFOFF (NREC*512) // float area offset (halves) inside d_ws

typedef __attribute__((ext_vector_type(8)))  _Float16 half8;
typedef __attribute__((ext_vector_type(4)))  _Float16 half4v;
typedef __attribute__((ext_vector_type(16))) float    f32x16;

__device__ __forceinline__ int uni(int v){ return __builtin_amdgcn_readfirstlane(v); }

// Unrolled (compile-time K) bias fold: sum_ci (sum_tap W[co][ci][tap]) * t_prev[ci].
template<int K>
__device__ __forceinline__ float fold_bias(const float* __restrict__ W, int co,
    const float* __restrict__ gp, const float* __restrict__ bbp,
    const float* __restrict__ rmp, const float* __restrict__ rvp)
{
    float acc = 0.f;
#pragma unroll
    for (int ci = 0; ci < 32; ++ci) {
        float sp = gp[ci] * rsqrtf(rvp[ci] + 1e-5f);
        float tp = bbp[ci] - rmp[ci]*sp;
        float wsum = 0.f;
#pragma unroll
        for (int tap = 0; tap < K; ++tap) wsum += W[(co*32 + ci)*K + tap];
        acc += wsum * tp;
    }
    return acc;
}

// ---------------- prep ----------------
// A-records for mfma_f32_32x32x16_f16: A[m=co=lane&31][k=(lane>>5)*8+j].
//  rec 0      : L0 tap-packed: k = tap*4+ci (k<12), W0 raw (no prev BN). k>=12 -> 0.
//  rec 1..6   : L1 (tap,cib): W1[co][ci=cib*16+k'] * s0[ci]
//  rec 7..16  : L2 likewise with s1;  rec 17..30: L3 with s2
//  rec 31..32 : MLP: fw1[co][ci]*s3[ci] for co<16, rows 16..31 zero.
// Float area: [4][32]{bias', oob_const} then fb1'[16] (identical scheme to the
// verified predecessor: stored act r satisfies a = s*r + t; seq-OOB stores -t/s).
extern "C" __global__ void prep_kernel(
    const float* w0, const float* w1, const float* w2, const float* w3,
    const float* b0, const float* g0, const float* bb0, const float* rm0, const float* rv0,
    const float* b1, const float* g1, const float* bb1, const float* rm1, const float* rv1,
    const float* b2, const float* g2, const float* bb2, const float* rm2, const float* rv2,
    const float* b3, const float* g3, const float* bb3, const float* rm3, const float* rv3,
    const float* fw1, const float* fb1, _Float16* ws)
{
    const int tid = threadIdx.x;
    const int rec = blockIdx.x;
    if (rec < NREC) {
        if (tid < 64) {
            const int lane = tid, co = lane & 31, hi = lane >> 5;
            half8 h;
            if (rec == 0) {
#pragma unroll
                for (int j = 0; j < 8; ++j) {
                    int k = hi*8 + j;
                    float wv = 0.f;
                    if (k < 12) wv = w0[(co*4 + (k & 3))*3 + (k >> 2)];
                    h[j] = (_Float16)wv;
                }
            } else if (rec < 31) {
                const float* W; const float *gp, *rvp; int K, r2;
                if      (rec < 7)  { W = w1; K = 3; r2 = rec - 1;  gp = g0; rvp = rv0; }
                else if (rec < 17) { W = w2; K = 5; r2 = rec - 7;  gp = g1; rvp = rv1; }
                else               { W = w3; K = 7; r2 = rec - 17; gp = g2; rvp = rv2; }
                const int tap = r2 >> 1, cib = r2 & 1;
#pragma unroll
                for (int j = 0; j < 8; ++j) {
                    int ci = cib*16 + hi*8 + j;
                    float s = gp[ci] * rsqrtf(rvp[ci] + 1e-5f);
                    h[j] = (_Float16)(W[(co*32 + ci)*K + tap] * s);
                }
            } else {
                const int cib = rec - 31;
#pragma unroll
                for (int j = 0; j < 8; ++j) {
                    int ci = cib*16 + hi*8 + j;
                    float s = g3[ci] * rsqrtf(rv3[ci] + 1e-5f);
                    h[j] = (_Float16)((co < 16) ? fw1[co*32 + ci]*s : 0.f);
                }
            }
            *(half8*)(ws + rec*512 + lane*8) = h;
        }
    } else {
        float* fa = (float*)(ws + BN_HALFOFF);
        if (tid < 128) {
            int l = tid >> 5, co = tid & 31;
            const float *g, *bb, *rm, *rv, *bi;
            if      (l == 0) { g=g0; bb=bb0; rm=rm0; rv=rv0; bi=b0; }
            else if (l == 1) { g=g1; bb=bb1; rm=rm1; rv=rv1; bi=b1; }
            else if (l == 2) { g=g2; bb=bb2; rm=rm2; rv=rv2; bi=b2; }
            else             { g=g3; bb=bb3; rm=rm3; rv=rv3; bi=b3; }
            float s = g[co] * rsqrtf(rv[co] + 1e-5f);
            float t = bb[co] - rm[co]*s;
            float bias = bi[co];
            if      (l == 1) bias += fold_bias<3>(w1, co, g0, bb0, rm0, rv0);
            else if (l == 2) bias += fold_bias<5>(w2, co, g1, bb1, rm1, rv1);
            else if (l == 3) bias += fold_bias<7>(w3, co, g2, bb2, rm2, rv2);
            fa[(l*32 + co)*2 + 0] = bias;
            fa[(l*32 + co)*2 + 1] = -t / s;    // stored value at seq-OOB output positions
        } else if (tid < 144) {
            int hh = tid - 128;
            float acc = fb1[hh];
#pragma unroll
            for (int c = 0; c < 32; ++c) {
                float s3 = g3[c] * rsqrtf(rv3[c] + 1e-5f);
                float t3 = bb3[c] - rm3[c]*s3;
                acc += fw1[hh*32 + c] * t3;
            }
            fa[256 + hh] = acc;                // fb1'
        }
    }
}

// ---------------- conv epilogue (shared) ----------------
// C/D of mfma_f32_32x32x16: col = lane&31 = position, row(co) = (r&3)+8*(r>>2)+4*hi.
// Lane holds 4 groups of 4 consecutive co; group g -> chunk g>>1, half4 store.
__device__ __forceinline__ void conv_epi(
    f32x16* acc, const float2* __restrict__ bo,
    _Float16* outb, int s0, int doff, int P0, int n, int hi)
{
    float2 pv[16];
#pragma unroll
    for (int g = 0; g < 4; ++g)
#pragma unroll
        for (int i = 0; i < 4; ++i) pv[g*4 + i] = bo[g*8 + 4*hi + i];

#pragma unroll
    for (int t = 0; t < 2; ++t) {
        const int pos = P0 + t*32 + n;
        const bool oob = (unsigned)(s0 + doff + pos) >= SEQ;
#pragma unroll
        for (int g = 0; g < 4; ++g) {
            half4v hv;
#pragma unroll
            for (int i = 0; i < 4; ++i) {
                const float2 p = pv[g*4 + i];
                const float v = fmaxf(acc[t][g*4 + i] + p.x, 0.f);
                hv[i] = (_Float16)(oob ? p.y : v);
            }
            *(half4v*)(outb + (g >> 1)*CSH + pos*16 + (g & 1)*8 + hi*4) = hv;
        }
    }
}

// ---------------- conv layer (L1..L3), 32x32x16 ----------------
// LDS layout: chunk cib holds ci [16cib..16cib+15]; row = 16 halves (32B).
// B-frag lane (n=lane&31, hi=lane>>5): 16B at cib*CSH + (P0+n+tap)*16 + hi*8
//  -> 64 lanes cover a contiguous 1KB region (conflict-free).
template<int K, int DOFF>
__device__ __forceinline__ void conv32(
    const _Float16* __restrict__ rec, const float2* __restrict__ bo,
    const _Float16* in, _Float16* outb, int s0, int P0, int lane)
{
    const int n = lane & 31, hi = lane >> 5;
    const _Float16* bbase = in + (P0 + n)*16 + hi*8;

    f32x16 acc[2];
#pragma unroll
    for (int t = 0; t < 2; ++t)
#pragma unroll
        for (int i = 0; i < 16; ++i) acc[t][i] = 0.f;

#pragma unroll
    for (int tap = 0; tap < K; ++tap) {
        half8 a0 = *(const half8*)(rec + (tap*2 + 0)*512 + lane*8);
        half8 a1 = *(const half8*)(rec + (tap*2 + 1)*512 + lane*8);
#pragma unroll
        for (int t = 0; t < 2; ++t) {
            half8 b0 = *(const half8*)(bbase + 0*CSH + (t*32 + tap)*16);
            half8 b1 = *(const half8*)(bbase + 1*CSH + (t*32 + tap)*16);
            acc[t] = __builtin_amdgcn_mfma_f32_32x32x16_f16(a0, b0, acc[t], 0, 0, 0);
            acc[t] = __builtin_amdgcn_mfma_f32_32x32x16_f16(a1, b1, acc[t], 0, 0, 0);
        }
    }
    conv_epi(acc, bo, outb, s0, DOFF, P0, n, hi);
}

// L0: tap-packed single MFMA per tile; B row = staged row (taps folded into k).
__device__ __forceinline__ void conv32L0(
    const _Float16* __restrict__ rec, const float2* __restrict__ bo,
    const _Float16* in, _Float16* outb, int s0, int P0, int lane)
{
    const int n = lane & 31, hi = lane >> 5;
    half8 a = *(const half8*)(rec + lane*8);
    f32x16 acc[2];
#pragma unroll
    for (int t = 0; t < 2; ++t)
#pragma unroll
        for (int i = 0; i < 16; ++i) acc[t][i] = 0.f;
#pragma unroll
    for (int t = 0; t < 2; ++t) {
        half8 b = *(const half8*)(in + (P0 + t*32 + n)*16 + hi*8);
        acc[t] = __builtin_amdgcn_mfma_f32_32x32x16_f16(a, b, acc[t], 0, 0, 0);
    }
    conv_epi(acc, bo, outb, s0, -6, P0, n, hi);
}

// Buffer origins: staged=s0-7(+tap in k), L0out=s0-6, L1out=s0-5, L2out=s0-3, L3out=s0.
// Validity: L0 valid 0..255, L1 0..253, L2 0..249, L3 0..243 = S_TILE-1. Reads beyond
// computed rows hit the zeroed pad rows 256..263 (finite, never consumed for valid rows).
extern "C" __global__ void __launch_bounds__(NTHR, 4)
dnashape_mfma(const float* __restrict__ x, const _Float16* __restrict__ ws,
              const float* __restrict__ fw2, const float* __restrict__ fb2,
              float* __restrict__ out)
{
    __shared__ _Float16 bufA[2*CSH] __attribute__((aligned(16)));  // 16.9 KB each
    __shared__ _Float16 bufB[2*CSH] __attribute__((aligned(16)));  // total 33.8 KB -> 4 blocks/CU

    const int tid = threadIdx.x;
    const int s0  = blockIdx.x * S_TILE;
    const int b   = blockIdx.y;

    // ---- stage: row r halves[k=tap*4+ci] = x[ci][s0-7+r+tap]; halves 12..15 = 0
    {
        const float* xb = x + b*4*SEQ;
        const int r  = tid;
        const int sb = s0 - 7 + r;
        _Float16 h[16];
#pragma unroll
        for (int tap = 0; tap < 3; ++tap) {
            const int sg = sb + tap;
            const bool ok = (unsigned)sg < SEQ;
#pragma unroll
            for (int ci = 0; ci < 4; ++ci)
                h[tap*4 + ci] = (_Float16)(ok ? xb[ci*SEQ + sg] : 0.f);
        }
#pragma unroll
        for (int j = 12; j < 16; ++j) h[j] = (_Float16)0.f;
        *(half8*)(bufB + r*16)     = *(half8*)(h);
        *(half8*)(bufB + r*16 + 8) = *(half8*)(h + 8);
        // zero pad rows 256..263, both chunks, both buffers (64 x half8 = 2KB)
        if (tid < 64) {
            const half8 z = {0,0,0,0,0,0,0,0};
            _Float16* base = (tid & 32) ? bufA : bufB;
            *(half8*)(base + ((tid >> 4) & 1)*CSH + 256*16 + (tid & 15)*8) = z;
        }
    }
    __syncthreads();

    const int lane = tid & 63;
    const int wv   = uni(tid >> 6);
    const int P0   = wv * 64;                 // wave owns two 32-pos tiles: P0, P0+32
    const float*  fa = (const float*)(ws + BN_HALFOFF);
    const float2* bo = (const float2*)fa;

    conv32L0     (ws,           bo,      bufB, bufA, s0, P0, lane);
    __syncthreads();
    conv32<3, -5>(ws + 1*512,   bo + 32, bufA, bufB, s0, P0, lane);
    __syncthreads();
    conv32<5, -3>(ws + 7*512,   bo + 64, bufB, bufA, s0, P0, lane);
    __syncthreads();
    conv32<7,  0>(ws + 17*512,  bo + 96, bufA, bufB, s0, P0, lane);
    __syncthreads();

    // ---- MLP 32 -> 16 (relu) -> 1 via one 32x32x16 pair per tile (rows co>=16 zero).
    {
        const int n = lane & 31, hi = lane >> 5;
        half8 am0 = *(const half8*)(ws + 31*512 + lane*8);
        half8 am1 = *(const half8*)(ws + 32*512 + lane*8);
        float fb1v[8], fw2v[8];
#pragma unroll
        for (int r = 0; r < 8; ++r) {
            const int co = (r & 3) + 8*(r >> 2) + 4*hi;   // lane's valid co (<16)
            fb1v[r] = fa[256 + co];
            fw2v[r] = fw2[co];
        }
        const float fb2v = fb2[0];
#pragma unroll
        for (int t = 0; t < 2; ++t) {
            const int pos = P0 + t*32 + n;
            half8 bf0 = *(const half8*)(bufB + 0*CSH + pos*16 + hi*8);
            half8 bf1 = *(const half8*)(bufB + 1*CSH + pos*16 + hi*8);
            f32x16 d;
#pragma unroll
            for (int i = 0; i < 16; ++i) d[i] = 0.f;
            d = __builtin_amdgcn_mfma_f32_32x32x16_f16(am0, bf0, d, 0, 0, 0);
            d = __builtin_amdgcn_mfma_f32_32x32x16_f16(am1, bf1, d, 0, 0, 0);
            float part = 0.f;
#pragma unroll
            for (int r = 0; r < 8; ++r)
                part += fmaxf(d[r] + fb1v[r], 0.f) * fw2v[r];
            part += __shfl_xor(part, 32, 64);   // combine hi=0 and hi=1 co-halves
            const int gpos = s0 + pos;
            if (hi == 0 && pos < S_TILE && gpos < SEQ)
                out[b*SEQ + gpos] = part + fb2v;
        }
    }
}

extern "C" void kernel_launch(void* const* d_in, const int* in_sizes, int n_in,
                              void* d_out, int out_size, void* d_ws, size_t ws_size,
                              hipStream_t stream) {
    const float* p[29];
    for (int i = 0; i < 29; ++i) p[i] = (const float*)d_in[i];
    _Float16* ws = (_Float16*)d_ws;   // needs 33*1024 + 1088 = 34880 B

    prep_kernel<<<dim3(NREC + 1), 144, 0, stream>>>(
        p[1], p[7], p[13], p[19],
        p[2], p[3], p[4], p[5], p[6],
        p[8], p[9], p[10], p[11], p[12],
        p[14], p[15], p[16], p[17], p[18],
        p[20], p[21], p[22], p[23], p[24],
        p[25], p[26], ws);

    dim3 grid((SEQ + S_TILE - 1) / S_TILE, 128);   // 34 x 128, 1 image per block
    dnashape_mfma<<<grid, NTHR, 0, stream>>>(p[0], (const _Float16*)ws,
                                             p[27], p[28], (float*)d_out);
}